// Round 1
// 365.940 us; speedup vs baseline: 1.0171x; 1.0171x over previous
//
#include <hip/hip_runtime.h>

#define TSTEPS 128
#define NIN 24
#define HD 128
#define BT 16
#define NBLK 128     // 2048 / BT
#define NTH 512

// LDS geometry (units: _Float16 elements)
#define RS    136               // h-panel row stride (16B-aligned rows, 2-way bank alias only)
#define SLOT  (BT*RS)           // 2176
#define H1B   (2*SLOT)          // h1 double buffer after h0 double buffer
#define W1B   (4*SLOT)          // 8704 : W_hh1 in MFMA-fragment order, 8 wv * 16 frags * 512
#define SM_ELTS (W1B + 8*16*512)    // 74240 f16
#define SM_BYTES (SM_ELTS*2)        // 148480 B  (< 160 KiB, dynamic LDS)

typedef _Float16 half8  __attribute__((ext_vector_type(8)));
typedef _Float16 half4v __attribute__((ext_vector_type(4)));
typedef float    floatx4 __attribute__((ext_vector_type(4)));

__device__ __forceinline__ float sigf(float x) {
    return __builtin_amdgcn_rcpf(1.0f + __expf(-x));
}
__device__ __forceinline__ float tanh_f(float x) {
    return 1.0f - 2.0f * __builtin_amdgcn_rcpf(1.0f + __expf(2.0f * x));
}

__device__ __forceinline__ half8 ldw8(const float* p) {
    const float4* q = (const float4*)p;
    float4 a = q[0], b = q[1];
    half8 r;
    r[0] = (_Float16)a.x; r[1] = (_Float16)a.y; r[2] = (_Float16)a.z; r[3] = (_Float16)a.w;
    r[4] = (_Float16)b.x; r[5] = (_Float16)b.y; r[6] = (_Float16)b.z; r[7] = (_Float16)b.w;
    return r;
}

__global__ __launch_bounds__(NTH, 2)
void lstm2_fused(const float* __restrict__ x,
                 const float* __restrict__ Wih0, const float* __restrict__ Whh0,
                 const float* __restrict__ bih0, const float* __restrict__ bhh0,
                 const float* __restrict__ Wih1, const float* __restrict__ Whh1,
                 const float* __restrict__ bih1, const float* __restrict__ bhh1,
                 const float* __restrict__ Wfc,  const float* __restrict__ bfc,
                 float* __restrict__ out)
{
    extern __shared__ __align__(16) _Float16 SM[];

    const int tid = threadIdx.x;
    const int blk = blockIdx.x;
    const int wv  = tid >> 6;
    const int ln  = tid & 63;
    const int qd  = ln >> 4;
    const int nn  = ln & 15;
    const int b0  = blk * BT;
    const int jc  = wv * 16 + nn;

    const half8 z8 = {0, 0, 0, 0, 0, 0, 0, 0};

    // ---- zero h0/h1 double buffers (slots read as "state -1" must be 0) ----
    for (int i = tid * 8; i < W1B; i += NTH * 8) *(half8*)&SM[i] = z8;

    // ---- combined biases + register weights: wih0, whh0, wih1 (144 VGPRs) ----
    float bias0[4], bias1[4];
    half8 wih0[4];
    half8 whh0[4][4];
    half8 wih1[4][4];
#pragma unroll
    for (int tI = 0; tI < 4; ++tI) {
        int g = tI * HD + wv * 16 + nn;
        bias0[tI] = bih0[g] + bhh0[g];
        bias1[tI] = bih1[g] + bhh1[g];
        wih0[tI] = (qd < 3) ? ldw8(Wih0 + g * NIN + qd * 8) : z8;
#pragma unroll
        for (int kk = 0; kk < 4; ++kk) {
            whh0[tI][kk] = ldw8(Whh0 + g * HD + kk * 32 + qd * 8);
            wih1[tI][kk] = ldw8(Wih1 + g * HD + kk * 32 + qd * 8);
        }
    }

    // ---- stage W_hh1 -> LDS in MFMA B-fragment order ----
    // frag (wv_,tI_,kk_) holds W[g][k], g = tI_*128+wv_*16+nn_, k = kk_*32+qd_*8+e,
    // stored at frag*512 + lane*8 + e  (lane = qd_*16+nn_): reads are one
    // ds_read_b128 per frag, compile-time offset, linear per-lane (conflict-free).
    for (int i = tid; i < 512 * 32; i += NTH) {
        int g  = i >> 5;
        int k0 = (i & 31) << 2;
        float4 v = *(const float4*)(Whh1 + g * HD + k0);
        half4v h; h[0] = (_Float16)v.x; h[1] = (_Float16)v.y;
                  h[2] = (_Float16)v.z; h[3] = (_Float16)v.w;
        int dst = W1B + ((((g >> 4) & 7) * 16) + (g >> 7) * 4 + (k0 >> 5)) * 512
                      + (((k0 >> 3) & 3) * 16 + (g & 15)) * 8 + (k0 & 7);
        *(half4v*)&SM[dst] = h;
    }

    // ---- x: 1-iteration register prefetch (no LDS staging) ----
    // lane (qd,nn) supplies A-frag row nn, k = qd*8..qd*8+7; qd==3 rows are
    // multiplied by wih0[..]=0, so clamp the address (finite garbage is fine).
    const float* xrow = x + (size_t)(b0 + nn) * (TSTEPS * NIN) + (qd < 3 ? qd * 8 : 16);
    float4 pf0 = *(const float4*)(xrow);
    float4 pf1 = *(const float4*)(xrow + 4);

    float cs0[4] = {0.f, 0.f, 0.f, 0.f};
    float cs1[4] = {0.f, 0.f, 0.f, 0.f};
    const int w1base = W1B + wv * 8192 + ln * 8;

    __syncthreads();   // zeros + W_hh1 staging visible

    // =============== iter 0: layer0 step 0 (h0[-1]=0, so only x MFMA) ===============
    {
        half8 ax;
        ax[0] = (_Float16)pf0.x; ax[1] = (_Float16)pf0.y; ax[2] = (_Float16)pf0.z; ax[3] = (_Float16)pf0.w;
        ax[4] = (_Float16)pf1.x; ax[5] = (_Float16)pf1.y; ax[6] = (_Float16)pf1.z; ax[7] = (_Float16)pf1.w;
        pf0 = *(const float4*)(xrow + NIN);
        pf1 = *(const float4*)(xrow + NIN + 4);

        floatx4 acc0[4];
#pragma unroll
        for (int tI = 0; tI < 4; ++tI) {
            floatx4 a0 = {bias0[tI], bias0[tI], bias0[tI], bias0[tI]};
            acc0[tI] = __builtin_amdgcn_mfma_f32_16x16x32_f16(ax, wih0[tI], a0, 0, 0, 0);
        }
#pragma unroll
        for (int r = 0; r < 4; ++r) {
            float iv = sigf(acc0[0][r]);
            float gv = tanh_f(acc0[2][r]);
            float ov = sigf(acc0[3][r]);
            float cn = iv * gv;            // c_prev = 0
            cs0[r] = cn;
            SM[(qd * 4 + r) * RS + jc] = (_Float16)(ov * tanh_f(cn));   // h0[0] -> slot 0
        }
    }

    // =============== main loop t = 1..127: layer0 step t + layer1 step t-1 ===============
#pragma unroll 1
    for (int t = 1; t < TSTEPS; ++t) {
        __syncthreads();   // h0[t-1], h1[t-2] visible; x prefetch drained

        half8 ax;
        ax[0] = (_Float16)pf0.x; ax[1] = (_Float16)pf0.y; ax[2] = (_Float16)pf0.z; ax[3] = (_Float16)pf0.w;
        ax[4] = (_Float16)pf1.x; ax[5] = (_Float16)pf1.y; ax[6] = (_Float16)pf1.z; ax[7] = (_Float16)pf1.w;
        {
            const int tn = (t < TSTEPS - 1) ? t + 1 : TSTEPS - 1;   // clamped re-load at t=127
            pf0 = *(const float4*)(xrow + tn * NIN);
            pf1 = *(const float4*)(xrow + tn * NIN + 4);
        }

        const int h0r = ((t - 1) & 1) * SLOT;
        const int h0w = (t & 1) * SLOT;
        const int h1r = H1B + (t & 1) * SLOT;            // h1[t-2]
        const int h1w = H1B + ((t & 1) ^ 1) * SLOT;      // h1[t-1]

        floatx4 acc0[4], acc1[4];
#pragma unroll
        for (int tI = 0; tI < 4; ++tI) {
            floatx4 a0 = {bias0[tI], bias0[tI], bias0[tI], bias0[tI]};
            acc0[tI] = __builtin_amdgcn_mfma_f32_16x16x32_f16(ax, wih0[tI], a0, 0, 0, 0);
            floatx4 a1 = {bias1[tI], bias1[tI], bias1[tI], bias1[tI]};
            acc1[tI] = a1;
        }

        // h0[t-1] feeds BOTH layer0 recurrence and layer1 input: one read, 8 MFMAs
#pragma unroll
        for (int kk = 0; kk < 4; ++kk) {
            const half8 ah = *(const half8*)&SM[h0r + nn * RS + kk * 32 + qd * 8];
#pragma unroll
            for (int tI = 0; tI < 4; ++tI)
                acc0[tI] = __builtin_amdgcn_mfma_f32_16x16x32_f16(ah, whh0[tI][kk], acc0[tI], 0, 0, 0);
#pragma unroll
            for (int tI = 0; tI < 4; ++tI)
                acc1[tI] = __builtin_amdgcn_mfma_f32_16x16x32_f16(ah, wih1[tI][kk], acc1[tI], 0, 0, 0);
        }

        // layer1 recurrence: h1[t-2] x W_hh1 (B-frags streamed from LDS)
#pragma unroll
        for (int kk = 0; kk < 4; ++kk) {
            const half8 a2 = *(const half8*)&SM[h1r + nn * RS + kk * 32 + qd * 8];
#pragma unroll
            for (int tI = 0; tI < 4; ++tI) {
                const half8 w1 = *(const half8*)&SM[w1base + (tI * 4 + kk) * 512];
                acc1[tI] = __builtin_amdgcn_mfma_f32_16x16x32_f16(a2, w1, acc1[tI], 0, 0, 0);
            }
        }

        // elementwise layer0 -> h0[t]
#pragma unroll
        for (int r = 0; r < 4; ++r) {
            float iv = sigf(acc0[0][r]);
            float fv = sigf(acc0[1][r]);
            float gv = tanh_f(acc0[2][r]);
            float ov = sigf(acc0[3][r]);
            float cn = fv * cs0[r] + iv * gv;
            cs0[r] = cn;
            SM[h0w + (qd * 4 + r) * RS + jc] = (_Float16)(ov * tanh_f(cn));
        }
        // elementwise layer1 -> h1[t-1]
#pragma unroll
        for (int r = 0; r < 4; ++r) {
            float iv = sigf(acc1[0][r]);
            float fv = sigf(acc1[1][r]);
            float gv = tanh_f(acc1[2][r]);
            float ov = sigf(acc1[3][r]);
            float cn = fv * cs1[r] + iv * gv;
            cs1[r] = cn;
            SM[h1w + (qd * 4 + r) * RS + jc] = (_Float16)(ov * tanh_f(cn));
        }
    }

    // =============== iter 128: layer1 step 127 only ===============
    {
        __syncthreads();
        floatx4 acc1[4];
#pragma unroll
        for (int tI = 0; tI < 4; ++tI) {
            floatx4 a1 = {bias1[tI], bias1[tI], bias1[tI], bias1[tI]};
            acc1[tI] = a1;
        }
#pragma unroll
        for (int kk = 0; kk < 4; ++kk) {
            const half8 ah = *(const half8*)&SM[SLOT + nn * RS + kk * 32 + qd * 8];   // h0[127] slot 1
#pragma unroll
            for (int tI = 0; tI < 4; ++tI)
                acc1[tI] = __builtin_amdgcn_mfma_f32_16x16x32_f16(ah, wih1[tI][kk], acc1[tI], 0, 0, 0);
        }
#pragma unroll
        for (int kk = 0; kk < 4; ++kk) {
            const half8 a2 = *(const half8*)&SM[H1B + nn * RS + kk * 32 + qd * 8];    // h1[126] slot 0
#pragma unroll
            for (int tI = 0; tI < 4; ++tI) {
                const half8 w1 = *(const half8*)&SM[w1base + (tI * 4 + kk) * 512];
                acc1[tI] = __builtin_amdgcn_mfma_f32_16x16x32_f16(a2, w1, acc1[tI], 0, 0, 0);
            }
        }
#pragma unroll
        for (int r = 0; r < 4; ++r) {
            float iv = sigf(acc1[0][r]);
            float fv = sigf(acc1[1][r]);
            float gv = tanh_f(acc1[2][r]);
            float ov = sigf(acc1[3][r]);
            float cn = fv * cs1[r] + iv * gv;
            SM[H1B + SLOT + (qd * 4 + r) * RS + jc] = (_Float16)(ov * tanh_f(cn));    // h1[127] slot 1
        }
    }
    __syncthreads();

    // =============== FC head: h1[127] is in h1 slot 1 ===============
    {
        int b = tid >> 5, sub = tid & 31;
        const _Float16* hp = &SM[H1B + SLOT + b * RS + sub * 4];
        const float4 wv4 = *(const float4*)(Wfc + sub * 4);
        float s = (float)hp[0] * wv4.x + (float)hp[1] * wv4.y
                + (float)hp[2] * wv4.z + (float)hp[3] * wv4.w;
        s += __shfl_down(s, 16, 32);
        s += __shfl_down(s, 8, 32);
        s += __shfl_down(s, 4, 32);
        s += __shfl_down(s, 2, 32);
        s += __shfl_down(s, 1, 32);
        if (sub == 0) out[b0 + b] = s + bfc[0];
    }
}

extern "C" void kernel_launch(void* const* d_in, const int* in_sizes, int n_in,
                              void* d_out, int out_size, void* d_ws, size_t ws_size,
                              hipStream_t stream) {
    static bool attr_set = false;
    if (!attr_set) {
        hipFuncSetAttribute(reinterpret_cast<const void*>(&lstm2_fused),
                            hipFuncAttributeMaxDynamicSharedMemorySize, SM_BYTES);
        attr_set = true;
    }
    const float* x    = (const float*)d_in[0];
    const float* Wih0 = (const float*)d_in[1];
    const float* Whh0 = (const float*)d_in[2];
    const float* bih0 = (const float*)d_in[3];
    const float* bhh0 = (const float*)d_in[4];
    const float* Wih1 = (const float*)d_in[5];
    const float* Whh1 = (const float*)d_in[6];
    const float* bih1 = (const float*)d_in[7];
    const float* bhh1 = (const float*)d_in[8];
    const float* Wfc  = (const float*)d_in[9];
    const float* bfc  = (const float*)d_in[10];
    float* out = (float*)d_out;

    lstm2_fused<<<dim3(NBLK), dim3(NTH), SM_BYTES, stream>>>(
        x, Wih0, Whh0, bih0, bhh0, Wih1, Whh1, bih1, bhh1, Wfc, bfc, out);
}